// Round 6
// baseline (140.049 us; speedup 1.0000x reference)
//
#include <hip/hip_runtime.h>
#include <stdint.h>

#define BATCH 32768
#define TANH_C 2.8853900817779268f   // 2/ln(2)

typedef __attribute__((ext_vector_type(8))) short short8;
typedef __attribute__((ext_vector_type(4))) float f32x4;
typedef __attribute__((ext_vector_type(4))) unsigned int u32x4;

__device__ __forceinline__ uint16_t bf16_rtne(float f) {
    union { float f; uint32_t u; } v; v.f = f;
    uint32_t u = v.u;
    u += 0x7fffu + ((u >> 16) & 1u);
    return (uint16_t)(u >> 16);
}

#if defined(__has_builtin)
#if __has_builtin(__builtin_amdgcn_cvt_pk_bf16_f32)
#define HAVE_CVT_PK_BF16 1
#endif
#endif

__device__ __forceinline__ uint32_t pack2_bf16(float a, float b) {
#ifdef HAVE_CVT_PK_BF16
    auto v = __builtin_amdgcn_cvt_pk_bf16_f32(a, b);
    uint32_t r; __builtin_memcpy(&r, &v, 4); return r;
#else
    return (uint32_t)bf16_rtne(a) | ((uint32_t)bf16_rtne(b) << 16);
#endif
}

// input already scaled by TANH_C: tanh(x) with a = TANH_C*x
__device__ __forceinline__ float tanh_pre(float a) {
    float e = __builtin_amdgcn_exp2f(a);
    return 1.0f - 2.0f * __builtin_amdgcn_rcpf(1.0f + e);
}

__device__ __forceinline__ float fast_tanh(float x) {
    return tanh_pre(x * TANH_C);
}

// ---------- kernel P: per-feature-d pack of B = W2g (bf16, MFMA frag order) ----------
// W2g[k=d*64+j][n] = sum_o W2[d,j,o] * Wg1[d*64+o, n]
__global__ __launch_bounds__(512) void kol_pack(const float* __restrict__ W2,
                                                const float* __restrict__ Wg1,
                                                uint16_t* __restrict__ Bp) {
    __shared__ __align__(16) float w2t[64 * 65];  // [o][j], stride 65
    __shared__ __align__(16) float g1s[64 * 64];  // [o][n]

    const int t = threadIdx.x;
    const int d = blockIdx.x;

    for (int f = t * 4; f < 4096; f += 2048) {
        float4 v = *(const float4*)&W2[(size_t)d * 4096 + f];
        int j = f >> 6, o = f & 63;   // W2[d][j][o..o+3]
        w2t[(o + 0) * 65 + j] = v.x;
        w2t[(o + 1) * 65 + j] = v.y;
        w2t[(o + 2) * 65 + j] = v.z;
        w2t[(o + 3) * 65 + j] = v.w;
        *(float4*)&g1s[f] = *(const float4*)&Wg1[(size_t)d * 4096 + f];
    }
    __syncthreads();

    const int jg = t >> 6;   // wave index = j-octet, wave-uniform
    const int n  = t & 63;
    float acc[8];
#pragma unroll
    for (int i = 0; i < 8; ++i) acc[i] = 0.f;

#pragma unroll 4
    for (int o = 0; o < 64; ++o) {
        float g = g1s[o * 64 + n];                 // 2-way alias = free
        const float* w = &w2t[o * 65 + jg * 8];    // wave-uniform broadcast
#pragma unroll
        for (int jj = 0; jj < 8; ++jj) acc[jj] = fmaf(w[jj], g, acc[jj]);
    }

    u32x4 pk;
    pk.x = pack2_bf16(acc[0], acc[1]);
    pk.y = pack2_bf16(acc[2], acc[3]);
    pk.z = pack2_bf16(acc[4], acc[5]);
    pk.w = pack2_bf16(acc[6], acc[7]);
    int off = ((d * 2 + (jg >> 2)) * 4 + (n >> 4)) * 64 + (jg & 3) * 16 + (n & 15);
    ((u32x4*)Bp)[off] = pk;   // contiguous 256B per 16-lane group
}

// ---------- kernel M: main fused GEMM, K-split over wave pairs ----------
// 1024 threads = 16 waves, 128 rows/block, 256 blocks -> 4 waves/SIMD.
// Waves 0-7: rows (w&7)*16.., d 0..31.  Waves 8-15: same rows, d 32..63.
// Partial C combined through LDS (dead xs region). cg computed redundantly
// per block from b2/Wg1 during staging (1 reg/lane/wave), folded at epilogue.
__global__ __launch_bounds__(1024, 4) void kol_main(
    const float* __restrict__ x, const float* __restrict__ W1, const float* __restrict__ b1,
    const uint16_t* __restrict__ Bp, const float* __restrict__ b2,
    const float* __restrict__ Wg1, const float* __restrict__ bg1,
    const float* __restrict__ Wg2, const float* __restrict__ bg2f,
    float* __restrict__ out) {
    __shared__ __align__(16) float smem[16896];   // 67584 B
    float* xs  = smem;            // [128*68] pre-scaled x   (later: cmb, 8192 f)
    float* w1s = smem + 8704;     // [4096]                  (later: part, 1024 f)
    float* b1s = smem + 12800;    // [4096] pre-scaled by TANH_C

    const int tid = threadIdx.x;
    const int wave = tid >> 6, lane = tid & 63;
    const int quad = lane >> 4, lm = lane & 15;
    const int rowbase = blockIdx.x * 128;

    // stage xs (8192 floats, 2 float4/thread)
#pragma unroll
    for (int ff = 0; ff < 2; ++ff) {
        int f = tid * 4 + ff * 4096;
        int r = f >> 6, c = f & 63;
        float4 v = *(const float4*)&x[(size_t)(rowbase + r) * 64 + c];
        v.x *= TANH_C; v.y *= TANH_C; v.z *= TANH_C; v.w *= TANH_C;
        *(float4*)&xs[r * 68 + c] = v;
    }
    // stage w1s/b1s (4096 floats each, 1 float4/thread)
    {
        int f = tid * 4;
        *(float4*)&w1s[f] = *(const float4*)&W1[f];
        float4 b = *(const float4*)&b1[f];
        b.x *= TANH_C; b.y *= TANH_C; b.z *= TANH_C; b.w *= TANH_C;
        *(float4*)&b1s[f] = b;
    }
    // cg partial: wave w covers m in [w*256, w*256+256), lane owns column n=lane
    float cgp;
    {
        const int m0 = wave * 256;
        float c0 = 0.f, c1 = 0.f, c2 = 0.f, c3 = 0.f;
#pragma unroll 2
        for (int m = 0; m < 256; m += 4) {
            c0 = fmaf(b2[m0 + m + 0], Wg1[(size_t)(m0 + m + 0) * 64 + lane], c0);
            c1 = fmaf(b2[m0 + m + 1], Wg1[(size_t)(m0 + m + 1) * 64 + lane], c1);
            c2 = fmaf(b2[m0 + m + 2], Wg1[(size_t)(m0 + m + 2) * 64 + lane], c2);
            c3 = fmaf(b2[m0 + m + 3], Wg1[(size_t)(m0 + m + 3) * 64 + lane], c3);
        }
        cgp = (c0 + c1) + (c2 + c3);
    }
    __syncthreads();

    f32x4 acc[4];
#pragma unroll
    for (int nt = 0; nt < 4; ++nt) acc[nt] = (f32x4){0.f, 0.f, 0.f, 0.f};

    const int w8 = wave & 7;
    const int dlo = (wave >> 3) * 32;
    const int myrow = w8 * 16 + lm;
    const float* xrow = &xs[myrow * 68];
    const short8* bbase = (const short8*)Bp + lane;

    // prime the pipeline with d=dlo's 8 B-fragments
    short8 bf[8];
    {
        const short8* bp0 = bbase + (size_t)dlo * 512;
#pragma unroll
        for (int i = 0; i < 8; ++i) bf[i] = bp0[i * 64];
    }

#pragma unroll 2
    for (int dd = 0; dd < 32; ++dd) {
        const int d = dlo + dd;
        // prefetch next iteration's B fragments
        short8 bn[8];
        const short8* bpn = bbase + (size_t)((d + 1) & 63) * 512;
#pragma unroll
        for (int i = 0; i < 8; ++i) bn[i] = bpn[i * 64];

        const float xv = xrow[d];
        const float* wq = &w1s[d * 64 + quad * 8];
        const float* bq = &b1s[d * 64 + quad * 8];
        float4 wA = *(const float4*)&wq[0];
        float4 wB = *(const float4*)&wq[4];
        float4 wC = *(const float4*)&wq[32];
        float4 wD = *(const float4*)&wq[36];
        float4 bA = *(const float4*)&bq[0];
        float4 bB = *(const float4*)&bq[4];
        float4 bC = *(const float4*)&bq[32];
        float4 bD = *(const float4*)&bq[36];

        union { short8 s; uint32_t u[4]; } a0, a1;
        a0.u[0] = pack2_bf16(tanh_pre(fmaf(xv, wA.x, bA.x)), tanh_pre(fmaf(xv, wA.y, bA.y)));
        a0.u[1] = pack2_bf16(tanh_pre(fmaf(xv, wA.z, bA.z)), tanh_pre(fmaf(xv, wA.w, bA.w)));
        a0.u[2] = pack2_bf16(tanh_pre(fmaf(xv, wB.x, bB.x)), tanh_pre(fmaf(xv, wB.y, bB.y)));
        a0.u[3] = pack2_bf16(tanh_pre(fmaf(xv, wB.z, bB.z)), tanh_pre(fmaf(xv, wB.w, bB.w)));
        a1.u[0] = pack2_bf16(tanh_pre(fmaf(xv, wC.x, bC.x)), tanh_pre(fmaf(xv, wC.y, bC.y)));
        a1.u[1] = pack2_bf16(tanh_pre(fmaf(xv, wC.z, bC.z)), tanh_pre(fmaf(xv, wC.w, bC.w)));
        a1.u[2] = pack2_bf16(tanh_pre(fmaf(xv, wD.x, bD.x)), tanh_pre(fmaf(xv, wD.y, bD.y)));
        a1.u[3] = pack2_bf16(tanh_pre(fmaf(xv, wD.z, bD.z)), tanh_pre(fmaf(xv, wD.w, bD.w)));

#pragma unroll
        for (int nt = 0; nt < 4; ++nt)
            acc[nt] = __builtin_amdgcn_mfma_f32_16x16x32_bf16(a0.s, bf[nt], acc[nt], 0, 0, 0);
#pragma unroll
        for (int nt = 0; nt < 4; ++nt)
            acc[nt] = __builtin_amdgcn_mfma_f32_16x16x32_bf16(a1.s, bf[4 + nt], acc[nt], 0, 0, 0);

#pragma unroll
        for (int i = 0; i < 8; ++i) bf[i] = bn[i];
    }

    // ---- combine K-halves + cg partials through LDS (xs/w1s now dead) ----
    __syncthreads();
    float* cmb  = xs;    // 8192 floats: high waves' acc
    float* part = w1s;   // 1024 floats: 16 wave cg partials
    if (wave >= 8) {
        int cb = ((wave - 8) * 64 + lane) * 16;
#pragma unroll
        for (int nt = 0; nt < 4; ++nt) *(f32x4*)&cmb[cb + nt * 4] = acc[nt];
    }
    part[wave * 64 + lane] = cgp;
    __syncthreads();

    if (wave < 8) {
        int cb = (wave * 64 + lane) * 16;
#pragma unroll
        for (int nt = 0; nt < 4; ++nt) {
            f32x4 o = *(const f32x4*)&cmb[cb + nt * 4];
            acc[nt] = acc[nt] + o;
        }
        // epilogue: out[b] = bg2 + sum_n Wg2[n] * tanh(C[b,n] + cg[n])
        float wg2v[4], cgv[4];
#pragma unroll
        for (int nt = 0; nt < 4; ++nt) {
            int n = nt * 16 + lm;
            float c = bg1[n];
#pragma unroll
            for (int w = 0; w < 16; ++w) c += part[w * 64 + n];
            cgv[nt] = c;
            wg2v[nt] = Wg2[n];
        }
        const float bg2 = bg2f[0];
#pragma unroll
        for (int r = 0; r < 4; ++r) {
            float s = 0.f;
#pragma unroll
            for (int nt = 0; nt < 4; ++nt)
                s += wg2v[nt] * fast_tanh(acc[nt][r] + cgv[nt]);
            s += __shfl_xor(s, 1, 64);
            s += __shfl_xor(s, 2, 64);
            s += __shfl_xor(s, 4, 64);
            s += __shfl_xor(s, 8, 64);
            if (lm == 0) {
                int row = rowbase + w8 * 16 + quad * 4 + r;
                out[row] = s + bg2;
            }
        }
    }
}

extern "C" void kernel_launch(void* const* d_in, const int* in_sizes, int n_in,
                              void* d_out, int out_size, void* d_ws, size_t ws_size,
                              hipStream_t stream) {
    const float* x   = (const float*)d_in[0];
    const float* W1  = (const float*)d_in[1];
    const float* b1  = (const float*)d_in[2];
    const float* W2  = (const float*)d_in[3];
    const float* b2  = (const float*)d_in[4];
    const float* Wg1 = (const float*)d_in[5];
    const float* bg1 = (const float*)d_in[6];
    const float* Wg2 = (const float*)d_in[7];
    const float* bg2 = (const float*)d_in[8];
    float* out = (float*)d_out;

    // ws usage: Bp only (512 KB) — strictly within proven budget.
    uint16_t* Bp = (uint16_t*)d_ws;

    kol_pack<<<64, 512, 0, stream>>>(W2, Wg1, Bp);
    kol_main<<<BATCH / 128, 1024, 0, stream>>>(x, W1, b1, Bp, b2, Wg1, bg1, Wg2, bg2, out);
}

// Round 7
// 126.859 us; speedup vs baseline: 1.1040x; 1.1040x over previous
//
#include <hip/hip_runtime.h>
#include <stdint.h>

#define BATCH 32768
#define TANH_C 2.8853900817779268f   // 2/ln(2)

typedef __attribute__((ext_vector_type(8))) short short8;
typedef __attribute__((ext_vector_type(4))) float f32x4;
typedef __attribute__((ext_vector_type(4))) unsigned int u32x4;

__device__ __forceinline__ uint16_t bf16_rtne(float f) {
    union { float f; uint32_t u; } v; v.f = f;
    uint32_t u = v.u;
    u += 0x7fffu + ((u >> 16) & 1u);
    return (uint16_t)(u >> 16);
}

#if defined(__has_builtin)
#if __has_builtin(__builtin_amdgcn_cvt_pk_bf16_f32)
#define HAVE_CVT_PK_BF16 1
#endif
#endif

__device__ __forceinline__ uint32_t pack2_bf16(float a, float b) {
#ifdef HAVE_CVT_PK_BF16
    auto v = __builtin_amdgcn_cvt_pk_bf16_f32(a, b);
    uint32_t r; __builtin_memcpy(&r, &v, 4); return r;
#else
    return (uint32_t)bf16_rtne(a) | ((uint32_t)bf16_rtne(b) << 16);
#endif
}

// two tanh's (args pre-scaled by TANH_C) sharing ONE v_rcp via 1/(d1*d2)
__device__ __forceinline__ uint32_t tanh2_pack(float a, float b) {
    float ea = __builtin_amdgcn_exp2f(a);
    float eb = __builtin_amdgcn_exp2f(b);
    float da = 1.0f + ea, db = 1.0f + eb;
    float ir = __builtin_amdgcn_rcpf(da * db);
    float ha = fmaf(-2.0f * db, ir, 1.0f);
    float hb = fmaf(-2.0f * da, ir, 1.0f);
    return pack2_bf16(ha, hb);
}

__device__ __forceinline__ float fast_tanh(float x) {
    float e = __builtin_amdgcn_exp2f(x * TANH_C);
    return 1.0f - 2.0f * __builtin_amdgcn_rcpf(1.0f + e);
}

// ---------- kernel P: per-feature-d pack of B = W2g (bf16, MFMA frag order) ----------
// W2g[k=d*64+j][n] = sum_o W2[d,j,o] * Wg1[d*64+o, n]
// Also emits cgpart[d][n] = sum_o b2[d,o]*Wg1[d*64+o,n] into d_out scratch.
__global__ __launch_bounds__(512) void kol_pack(const float* __restrict__ W2,
                                                const float* __restrict__ Wg1,
                                                const float* __restrict__ b2,
                                                uint16_t* __restrict__ Bp,
                                                float* __restrict__ cgpart) {
    __shared__ __align__(16) float w2t[64 * 65];  // [o][j], stride 65
    __shared__ __align__(16) float g1s[64 * 64];  // [o][n]

    const int t = threadIdx.x;
    const int d = blockIdx.x;

    for (int f = t * 4; f < 4096; f += 2048) {
        float4 v = *(const float4*)&W2[(size_t)d * 4096 + f];
        int j = f >> 6, o = f & 63;   // W2[d][j][o..o+3]
        w2t[(o + 0) * 65 + j] = v.x;
        w2t[(o + 1) * 65 + j] = v.y;
        w2t[(o + 2) * 65 + j] = v.z;
        w2t[(o + 3) * 65 + j] = v.w;
        *(float4*)&g1s[f] = *(const float4*)&Wg1[(size_t)d * 4096 + f];
    }
    __syncthreads();

    const int jg = t >> 6;   // wave index = j-octet, wave-uniform
    const int n  = t & 63;
    float acc[8];
#pragma unroll
    for (int i = 0; i < 8; ++i) acc[i] = 0.f;

#pragma unroll 4
    for (int o = 0; o < 64; ++o) {
        float g = g1s[o * 64 + n];                 // 2-way alias = free
        const float* w = &w2t[o * 65 + jg * 8];    // wave-uniform broadcast
#pragma unroll
        for (int jj = 0; jj < 8; ++jj) acc[jj] = fmaf(w[jj], g, acc[jj]);
    }

    u32x4 pk;
    pk.x = pack2_bf16(acc[0], acc[1]);
    pk.y = pack2_bf16(acc[2], acc[3]);
    pk.z = pack2_bf16(acc[4], acc[5]);
    pk.w = pack2_bf16(acc[6], acc[7]);
    int off = ((d * 2 + (jg >> 2)) * 4 + (n >> 4)) * 64 + (jg & 3) * 16 + (n & 15);
    ((u32x4*)Bp)[off] = pk;   // contiguous 256B per 16-lane group

    // cg partial for this d (wave 0 only; b2 row is wave-uniform)
    if (t < 64) {
        float a = 0.f;
        const float* b2d = &b2[(size_t)d * 64];
#pragma unroll 4
        for (int o = 0; o < 64; ++o)
            a = fmaf(b2d[o], g1s[o * 64 + t], a);
        cgpart[d * 64 + t] = a;
    }
}

// ---------- kernel R: cg[n] = bg1[n] + sum_d cgpart[d][n]  (tiny, deterministic) ----------
__global__ __launch_bounds__(256) void kol_reduce_cg(const float* __restrict__ cgpart,
                                                     const float* __restrict__ bg1,
                                                     float* __restrict__ cg) {
    __shared__ float red[4][64];
    const int t = threadIdx.x;
    const int n = t & 63, seg = t >> 6;
    float a = 0.f;
#pragma unroll 4
    for (int d = seg * 16; d < seg * 16 + 16; ++d)
        a += cgpart[d * 64 + n];
    red[seg][n] = a;
    __syncthreads();
    if (t < 64)
        cg[n] = bg1[n] + red[0][n] + red[1][n] + red[2][n] + red[3][n];
}

// ---------- kernel M: main fused GEMM, K-split, 512 thr / 64 rows / 512 blocks ----------
// wave w: row-group w&3 (16 rows), K-half w>>2 (d 0..31 or 32..63).
// 2 blocks/CU -> 4 waves/SIMD. No K-loop barriers; B prefetched 1 iter ahead.
__global__ __launch_bounds__(512, 4) void kol_main(
    const float* __restrict__ x, const float* __restrict__ W1, const float* __restrict__ b1,
    const uint16_t* __restrict__ Bp, const float* __restrict__ cg,
    const float* __restrict__ Wg2, const float* __restrict__ bg2f,
    float* __restrict__ out) {
    __shared__ __align__(16) float xs[64 * 68];    // pre-scaled x; later cmb[256][17]
    __shared__ __align__(16) float w1s[4096];
    __shared__ __align__(16) float b1s[4096];      // pre-scaled by TANH_C

    const int tid = threadIdx.x;
    const int wave = tid >> 6, lane = tid & 63;
    const int quad = lane >> 4, lm = lane & 15;
    const int w4 = wave & 3, kh = wave >> 2;
    const int rowbase = blockIdx.x * 64;

#pragma unroll
    for (int ff = 0; ff < 2; ++ff) {
        int f = tid * 4 + ff * 2048;
        int r = f >> 6, c = f & 63;
        float4 v = *(const float4*)&x[(size_t)(rowbase + r) * 64 + c];
        v.x *= TANH_C; v.y *= TANH_C; v.z *= TANH_C; v.w *= TANH_C;
        *(float4*)&xs[r * 68 + c] = v;
        *(float4*)&w1s[f] = *(const float4*)&W1[f];
        float4 b = *(const float4*)&b1[f];
        b.x *= TANH_C; b.y *= TANH_C; b.z *= TANH_C; b.w *= TANH_C;
        *(float4*)&b1s[f] = b;
    }
    __syncthreads();

    f32x4 acc[4];
#pragma unroll
    for (int nt = 0; nt < 4; ++nt) acc[nt] = (f32x4){0.f, 0.f, 0.f, 0.f};

    const int dlo = kh * 32;
    const int myrow = w4 * 16 + lm;
    const float* xrow = &xs[myrow * 68];
    const short8* bbase = (const short8*)Bp + lane;

    // prime the pipeline with d=dlo's 8 B-fragments
    short8 bf[8];
    {
        const short8* bp0 = bbase + (size_t)dlo * 512;
#pragma unroll
        for (int i = 0; i < 8; ++i) bf[i] = bp0[i * 64];
    }

#pragma unroll 2
    for (int dd = 0; dd < 32; ++dd) {
        const int d = dlo + dd;
        // prefetch next iteration's B fragments (wraps within K-half on last iter)
        short8 bn[8];
        const short8* bpn = bbase + (size_t)(dlo + ((dd + 1) & 31)) * 512;
#pragma unroll
        for (int i = 0; i < 8; ++i) bn[i] = bpn[i * 64];

        const float xv = xrow[d];
        const float* wq = &w1s[d * 64 + quad * 8];
        const float* bq = &b1s[d * 64 + quad * 8];
        float4 wA = *(const float4*)&wq[0];
        float4 wB = *(const float4*)&wq[4];
        float4 wC = *(const float4*)&wq[32];
        float4 wD = *(const float4*)&wq[36];
        float4 bA = *(const float4*)&bq[0];
        float4 bB = *(const float4*)&bq[4];
        float4 bC = *(const float4*)&bq[32];
        float4 bD = *(const float4*)&bq[36];

        union { short8 s; uint32_t u[4]; } a0, a1;
        a0.u[0] = tanh2_pack(fmaf(xv, wA.x, bA.x), fmaf(xv, wA.y, bA.y));
        a0.u[1] = tanh2_pack(fmaf(xv, wA.z, bA.z), fmaf(xv, wA.w, bA.w));
        a0.u[2] = tanh2_pack(fmaf(xv, wB.x, bB.x), fmaf(xv, wB.y, bB.y));
        a0.u[3] = tanh2_pack(fmaf(xv, wB.z, bB.z), fmaf(xv, wB.w, bB.w));
        a1.u[0] = tanh2_pack(fmaf(xv, wC.x, bC.x), fmaf(xv, wC.y, bC.y));
        a1.u[1] = tanh2_pack(fmaf(xv, wC.z, bC.z), fmaf(xv, wC.w, bC.w));
        a1.u[2] = tanh2_pack(fmaf(xv, wD.x, bD.x), fmaf(xv, wD.y, bD.y));
        a1.u[3] = tanh2_pack(fmaf(xv, wD.z, bD.z), fmaf(xv, wD.w, bD.w));

#pragma unroll
        for (int nt = 0; nt < 4; ++nt)
            acc[nt] = __builtin_amdgcn_mfma_f32_16x16x32_bf16(a0.s, bf[nt], acc[nt], 0, 0, 0);
#pragma unroll
        for (int nt = 0; nt < 4; ++nt)
            acc[nt] = __builtin_amdgcn_mfma_f32_16x16x32_bf16(a1.s, bf[4 + nt], acc[nt], 0, 0, 0);

#pragma unroll
        for (int i = 0; i < 8; ++i) bf[i] = bn[i];
    }

    // ---- combine K-halves through LDS (xs now dead; stride 17 = conflict-light) ----
    __syncthreads();
    float* cmb = xs;   // [256][17] floats, max index 255*17+16 = 4351 == 64*68-1
    if (kh == 1) {
        int cb = (w4 * 64 + lane) * 17;
#pragma unroll
        for (int nt = 0; nt < 4; ++nt) *(f32x4*)&cmb[cb + nt * 4] = acc[nt];
    }
    __syncthreads();

    if (kh == 0) {
        int cb = (w4 * 64 + lane) * 17;
#pragma unroll
        for (int nt = 0; nt < 4; ++nt) {
            f32x4 o = *(const f32x4*)&cmb[cb + nt * 4];
            acc[nt] = acc[nt] + o;
        }
        // epilogue: out[b] = bg2 + sum_n Wg2[n] * tanh(C[b,n] + cg[n])   (cg includes bg1)
        float wg2v[4], cgv[4];
#pragma unroll
        for (int nt = 0; nt < 4; ++nt) {
            wg2v[nt] = Wg2[nt * 16 + lm];
            cgv[nt]  = cg[nt * 16 + lm];
        }
        const float bg2 = bg2f[0];
#pragma unroll
        for (int r = 0; r < 4; ++r) {
            float s = 0.f;
#pragma unroll
            for (int nt = 0; nt < 4; ++nt)
                s += wg2v[nt] * fast_tanh(acc[nt][r] + cgv[nt]);
            s += __shfl_xor(s, 1, 64);
            s += __shfl_xor(s, 2, 64);
            s += __shfl_xor(s, 4, 64);
            s += __shfl_xor(s, 8, 64);
            if (lm == 0) {
                int row = rowbase + w4 * 16 + quad * 4 + r;
                out[row] = s + bg2;
            }
        }
    }
}

extern "C" void kernel_launch(void* const* d_in, const int* in_sizes, int n_in,
                              void* d_out, int out_size, void* d_ws, size_t ws_size,
                              hipStream_t stream) {
    const float* x   = (const float*)d_in[0];
    const float* W1  = (const float*)d_in[1];
    const float* b1  = (const float*)d_in[2];
    const float* W2  = (const float*)d_in[3];
    const float* b2  = (const float*)d_in[4];
    const float* Wg1 = (const float*)d_in[5];
    const float* bg1 = (const float*)d_in[6];
    const float* Wg2 = (const float*)d_in[7];
    const float* bg2 = (const float*)d_in[8];
    float* out = (float*)d_out;

    // ws: Bp 512KB + cg 256B = 524544B (proven). cgpart (16KB) in d_out (128KB):
    // written by kol_pack, read by kol_reduce_cg, fully overwritten by kol_main.
    uint16_t* Bp  = (uint16_t*)d_ws;
    float* cg     = (float*)((char*)d_ws + 4096 * 64 * 2);
    float* cgpart = out;

    kol_pack<<<64, 512, 0, stream>>>(W2, Wg1, b2, Bp, cgpart);
    kol_reduce_cg<<<1, 256, 0, stream>>>(cgpart, bg1, cg);
    kol_main<<<BATCH / 64, 512, 0, stream>>>(x, W1, b1, Bp, cg, Wg2, bg2, out);
}

// Round 8
// 124.304 us; speedup vs baseline: 1.1267x; 1.0206x over previous
//
#include <hip/hip_runtime.h>
#include <stdint.h>

#define BATCH 32768
#define TANH_C 2.8853900817779268f   // 2/ln(2)

typedef __attribute__((ext_vector_type(8))) short short8;
typedef __attribute__((ext_vector_type(4))) float f32x4;
typedef __attribute__((ext_vector_type(16))) float f32x16;
typedef __attribute__((ext_vector_type(4))) unsigned int u32x4;

__device__ __forceinline__ uint16_t bf16_rtne(float f) {
    union { float f; uint32_t u; } v; v.f = f;
    uint32_t u = v.u;
    u += 0x7fffu + ((u >> 16) & 1u);
    return (uint16_t)(u >> 16);
}

#if defined(__has_builtin)
#if __has_builtin(__builtin_amdgcn_cvt_pk_bf16_f32)
#define HAVE_CVT_PK_BF16 1
#endif
#endif

__device__ __forceinline__ uint32_t pack2_bf16(float a, float b) {
#ifdef HAVE_CVT_PK_BF16
    auto v = __builtin_amdgcn_cvt_pk_bf16_f32(a, b);
    uint32_t r; __builtin_memcpy(&r, &v, 4); return r;
#else
    return (uint32_t)bf16_rtne(a) | ((uint32_t)bf16_rtne(b) << 16);
#endif
}

// two tanh's (args pre-scaled by TANH_C) sharing ONE v_rcp via 1/(d1*d2)
__device__ __forceinline__ uint32_t tanh2_pack(float a, float b) {
    float ea = __builtin_amdgcn_exp2f(a);
    float eb = __builtin_amdgcn_exp2f(b);
    float da = 1.0f + ea, db = 1.0f + eb;
    float ir = __builtin_amdgcn_rcpf(da * db);
    float ha = fmaf(-2.0f * db, ir, 1.0f);
    float hb = fmaf(-2.0f * da, ir, 1.0f);
    return pack2_bf16(ha, hb);
}

__device__ __forceinline__ float fast_tanh(float x) {
    float e = __builtin_amdgcn_exp2f(x * TANH_C);
    return 1.0f - 2.0f * __builtin_amdgcn_rcpf(1.0f + e);
}

// ---------- kernel P: per-feature-d pack of B = W2g (bf16, 32x32x16 MFMA B order) ----
// W2g[k=d*64+j][n] = sum_o W2[d,j,o] * Wg1[d*64+o, n]
// B-frag for (d, chunk c, n-tile t): lane L holds k = d*64+c*16+(L>>5)*8+j, n = t*32+(L&31).
// flat u32x4 index = ((d*4+c)*2+t)*64 + ((k>>3)&1)*32 + (n&31)
// Also emits cgpart[d][n] into d_out scratch.
__global__ __launch_bounds__(512) void kol_pack(const float* __restrict__ W2,
                                                const float* __restrict__ Wg1,
                                                const float* __restrict__ b2,
                                                uint16_t* __restrict__ Bp,
                                                float* __restrict__ cgpart) {
    __shared__ __align__(16) float w2t[64 * 65];  // [o][j], stride 65
    __shared__ __align__(16) float g1s[64 * 64];  // [o][n]

    const int t = threadIdx.x;
    const int d = blockIdx.x;

    for (int f = t * 4; f < 4096; f += 2048) {
        float4 v = *(const float4*)&W2[(size_t)d * 4096 + f];
        int j = f >> 6, o = f & 63;   // W2[d][j][o..o+3]
        w2t[(o + 0) * 65 + j] = v.x;
        w2t[(o + 1) * 65 + j] = v.y;
        w2t[(o + 2) * 65 + j] = v.z;
        w2t[(o + 3) * 65 + j] = v.w;
        *(float4*)&g1s[f] = *(const float4*)&Wg1[(size_t)d * 4096 + f];
    }
    __syncthreads();

    const int jg = t >> 6;   // j-octet: k = d*64 + jg*8 + jj
    const int n  = t & 63;
    float acc[8];
#pragma unroll
    for (int i = 0; i < 8; ++i) acc[i] = 0.f;

#pragma unroll 4
    for (int o = 0; o < 64; ++o) {
        float g = g1s[o * 64 + n];
        const float* w = &w2t[o * 65 + jg * 8];
#pragma unroll
        for (int jj = 0; jj < 8; ++jj) acc[jj] = fmaf(w[jj], g, acc[jj]);
    }

    u32x4 pk;
    pk.x = pack2_bf16(acc[0], acc[1]);
    pk.y = pack2_bf16(acc[2], acc[3]);
    pk.z = pack2_bf16(acc[4], acc[5]);
    pk.w = pack2_bf16(acc[6], acc[7]);
    // c = jg>>1, hi = jg&1, tile = n>>5
    int off = ((d * 4 + (jg >> 1)) * 2 + (n >> 5)) * 64 + ((jg & 1) << 5) + (n & 31);
    ((u32x4*)Bp)[off] = pk;

    if (t < 64) {
        float a = 0.f;
        const float* b2d = &b2[(size_t)d * 64];
#pragma unroll 4
        for (int o = 0; o < 64; ++o)
            a = fmaf(b2d[o], g1s[o * 64 + t], a);
        cgpart[d * 64 + t] = a;
    }
}

// ---------- kernel R: cg[n] = bg1[n] + sum_d cgpart[d][n] ----------
__global__ __launch_bounds__(256) void kol_reduce_cg(const float* __restrict__ cgpart,
                                                     const float* __restrict__ bg1,
                                                     float* __restrict__ cg) {
    __shared__ float red[4][64];
    const int t = threadIdx.x;
    const int n = t & 63, seg = t >> 6;
    float a = 0.f;
#pragma unroll 4
    for (int d = seg * 16; d < seg * 16 + 16; ++d)
        a += cgpart[d * 64 + n];
    red[seg][n] = a;
    __syncthreads();
    if (t < 64)
        cg[n] = bg1[n] + red[0][n] + red[1][n] + red[2][n] + red[3][n];
}

// ---------- kernel M: main fused GEMM, 32x32x16 MFMA, M=32/wave, K-split x4 ----------
// 512 thr = 8 waves = 2 row-groups(32 rows) x 4 K-quarters(16 d). 64 rows/block,
// 512 blocks -> 2 blocks/CU, 4 waves/SIMD. Loads at top of iter, ~500cy tanh burst
// hides them in-iteration; MFMAs at the bottom. No K-loop barriers, no prefetch regs.
__global__ __launch_bounds__(512, 4) void kol_main(
    const float* __restrict__ x, const float* __restrict__ W1, const float* __restrict__ b1,
    const uint16_t* __restrict__ Bp, const float* __restrict__ cg,
    const float* __restrict__ Wg2, const float* __restrict__ bg2f,
    float* __restrict__ out) {
    __shared__ __align__(16) float smem[12544];   // 50176 B
    float* xs  = smem;            // 64*68 = 4352 floats, pre-scaled x
    float* w1s = smem + 4352;     // 4096
    float* b1s = smem + 8448;     // 4096, pre-scaled by TANH_C
    // combine overlay (after main loop): f32x4 cmb[8][6][64] = 49152 B over smem

    const int tid = threadIdx.x;
    const int wave = tid >> 6, lane = tid & 63;
    const int nn = lane & 31, hi = lane >> 5;
    const int rg = wave & 1, kq = wave >> 1;
    const int rowbase = blockIdx.x * 64;

#pragma unroll
    for (int ff = 0; ff < 2; ++ff) {
        int f = tid * 4 + ff * 2048;
        int r = f >> 6, c = f & 63;
        float4 v = *(const float4*)&x[(size_t)(rowbase + r) * 64 + c];
        v.x *= TANH_C; v.y *= TANH_C; v.z *= TANH_C; v.w *= TANH_C;
        *(float4*)&xs[r * 68 + c] = v;
        *(float4*)&w1s[f] = *(const float4*)&W1[f];
        float4 b = *(const float4*)&b1[f];
        b.x *= TANH_C; b.y *= TANH_C; b.z *= TANH_C; b.w *= TANH_C;
        *(float4*)&b1s[f] = b;
    }
    __syncthreads();

    f32x16 acc0 = {0.f}, acc1 = {0.f};
#pragma unroll
    for (int i = 0; i < 16; ++i) { acc0[i] = 0.f; acc1[i] = 0.f; }

    const u32x4* bp = (const u32x4*)Bp + lane;
    const float* xcol = &xs[(rg * 32 + nn) * 68];

#pragma unroll 2
    for (int dd = 0; dd < 16; ++dd) {
        const int d = kq * 16 + dd;
        // 8 B-fragment loads issued first (L1/L2-resident; hidden by tanh burst)
        const u32x4* bfp = bp + (size_t)d * 512;
        u32x4 bfr[8];
#pragma unroll
        for (int i = 0; i < 8; ++i) bfr[i] = bfp[i * 64];

        const float xv = xcol[d];
        short8 afr[4];
#pragma unroll
        for (int c = 0; c < 4; ++c) {
            const float* wq = &w1s[d * 64 + c * 16 + hi * 8];
            const float* bq = &b1s[d * 64 + c * 16 + hi * 8];
            float4 w0 = *(const float4*)&wq[0];
            float4 w1v = *(const float4*)&wq[4];
            float4 b0 = *(const float4*)&bq[0];
            float4 b1v = *(const float4*)&bq[4];
            union { short8 s; uint32_t u[4]; } a;
            a.u[0] = tanh2_pack(fmaf(xv, w0.x, b0.x), fmaf(xv, w0.y, b0.y));
            a.u[1] = tanh2_pack(fmaf(xv, w0.z, b0.z), fmaf(xv, w0.w, b0.w));
            a.u[2] = tanh2_pack(fmaf(xv, w1v.x, b1v.x), fmaf(xv, w1v.y, b1v.y));
            a.u[3] = tanh2_pack(fmaf(xv, w1v.z, b1v.z), fmaf(xv, w1v.w, b1v.w));
            afr[c] = a.s;
        }
#pragma unroll
        for (int c = 0; c < 4; ++c) {
            union { u32x4 u; short8 s; } b0c, b1c;
            b0c.u = bfr[c * 2 + 0];
            b1c.u = bfr[c * 2 + 1];
            acc0 = __builtin_amdgcn_mfma_f32_32x32x16_bf16(afr[c], b0c.s, acc0, 0, 0, 0);
            acc1 = __builtin_amdgcn_mfma_f32_32x32x16_bf16(afr[c], b1c.s, acc1, 0, 0, 0);
        }
    }

    // ---- combine 4 K-quarter partials through LDS (smem dead) ----
    __syncthreads();
    f32x4* cmb = (f32x4*)smem;   // [s 0..7][widx 0..5][lane]
    if (kq != 0) {
        const int widx = (kq - 1) * 2 + rg;
#pragma unroll
        for (int s = 0; s < 8; ++s) {
            const int base = (s & 3) * 4;
            f32x4 v;
            if (s < 4) v = (f32x4){acc0[base], acc0[base + 1], acc0[base + 2], acc0[base + 3]};
            else       v = (f32x4){acc1[base], acc1[base + 1], acc1[base + 2], acc1[base + 3]};
            cmb[(s * 6 + widx) * 64 + lane] = v;
        }
    }
    __syncthreads();

    if (kq == 0) {
#pragma unroll
        for (int s = 0; s < 8; ++s) {
            const int base = (s & 3) * 4;
            f32x4 v0 = cmb[(s * 6 + 0 + rg) * 64 + lane];
            f32x4 v1 = cmb[(s * 6 + 2 + rg) * 64 + lane];
            f32x4 v2 = cmb[(s * 6 + 4 + rg) * 64 + lane];
            f32x4 v = v0 + v1 + v2;
            if (s < 4) {
#pragma unroll
                for (int i = 0; i < 4; ++i) acc0[base + i] += v[i];
            } else {
#pragma unroll
                for (int i = 0; i < 4; ++i) acc1[base + i] += v[i];
            }
        }
        // epilogue: out[b] = bg2 + sum_n Wg2[n]*tanh(C[b,n]+cg[n])
        // C/D map: col = t*32+nn, row m = (r&3) + 8*(r>>2) + 4*hi
        const float cg0 = cg[nn],      cg1 = cg[32 + nn];
        const float wg0 = Wg2[nn],     wg1 = Wg2[32 + nn];
        const float bg2 = bg2f[0];
#pragma unroll
        for (int g = 0; g < 4; ++g) {
            float4 res;
#pragma unroll
            for (int rr = 0; rr < 4; ++rr) {
                const int r = g * 4 + rr;
                float s = wg0 * fast_tanh(acc0[r] + cg0) + wg1 * fast_tanh(acc1[r] + cg1);
                s += __shfl_xor(s, 1, 64);
                s += __shfl_xor(s, 2, 64);
                s += __shfl_xor(s, 4, 64);
                s += __shfl_xor(s, 8, 64);
                s += __shfl_xor(s, 16, 64);
                ((float*)&res)[rr] = s + bg2;
            }
            if (nn == 0)
                *(float4*)&out[rowbase + rg * 32 + 8 * g + 4 * hi] = res;
        }
    }
}

extern "C" void kernel_launch(void* const* d_in, const int* in_sizes, int n_in,
                              void* d_out, int out_size, void* d_ws, size_t ws_size,
                              hipStream_t stream) {
    const float* x   = (const float*)d_in[0];
    const float* W1  = (const float*)d_in[1];
    const float* b1  = (const float*)d_in[2];
    const float* W2  = (const float*)d_in[3];
    const float* b2  = (const float*)d_in[4];
    const float* Wg1 = (const float*)d_in[5];
    const float* bg1 = (const float*)d_in[6];
    const float* Wg2 = (const float*)d_in[7];
    const float* bg2 = (const float*)d_in[8];
    float* out = (float*)d_out;

    // ws: Bp 512KB + cg 256B (proven budget). cgpart (16KB) in d_out:
    // written by kol_pack, read by kol_reduce_cg, fully overwritten by kol_main.
    uint16_t* Bp  = (uint16_t*)d_ws;
    float* cg     = (float*)((char*)d_ws + 4096 * 64 * 2);
    float* cgpart = out;

    kol_pack<<<64, 512, 0, stream>>>(W2, Wg1, b2, Bp, cgpart);
    kol_reduce_cg<<<1, 256, 0, stream>>>(cgpart, bg1, cg);
    kol_main<<<BATCH / 64, 512, 0, stream>>>(x, W1, b1, Bp, cg, Wg2, bg2, out);
}

// Round 9
// 122.231 us; speedup vs baseline: 1.1458x; 1.0170x over previous
//
#include <hip/hip_runtime.h>
#include <stdint.h>

#define BATCH 32768
#define TANH_C 2.8853900817779268f   // 2/ln(2)

typedef __attribute__((ext_vector_type(8))) short short8;
typedef __attribute__((ext_vector_type(4))) float f32x4;
typedef __attribute__((ext_vector_type(16))) float f32x16;
typedef __attribute__((ext_vector_type(4))) unsigned int u32x4;

__device__ __forceinline__ uint16_t bf16_rtne(float f) {
    union { float f; uint32_t u; } v; v.f = f;
    uint32_t u = v.u;
    u += 0x7fffu + ((u >> 16) & 1u);
    return (uint16_t)(u >> 16);
}

__device__ __forceinline__ uint32_t pack2_bf16(float a, float b) {
    return (uint32_t)bf16_rtne(a) | ((uint32_t)bf16_rtne(b) << 16);
}

// round-to-nearest (half-up) bf16 pack: 2x v_add_u32 + 1x v_perm_b32
__device__ __forceinline__ uint32_t pack2_bf16_fast(float a, float b) {
    uint32_t ra = __builtin_bit_cast(uint32_t, a) + 0x8000u;
    uint32_t rb = __builtin_bit_cast(uint32_t, b) + 0x8000u;
#if defined(__has_builtin)
#if __has_builtin(__builtin_amdgcn_perm)
    return __builtin_amdgcn_perm(rb, ra, 0x07060302u);  // {rb.hi16, ra.hi16}
#else
    return (rb & 0xffff0000u) | (ra >> 16);
#endif
#else
    return (rb & 0xffff0000u) | (ra >> 16);
#endif
}

// two tanh's (args pre-scaled by TANH_C) sharing ONE v_rcp via 1/(d1*d2)
__device__ __forceinline__ uint32_t tanh2_pack(float a, float b) {
    float ea = __builtin_amdgcn_exp2f(a);
    float eb = __builtin_amdgcn_exp2f(b);
    float da = 1.0f + ea, db = 1.0f + eb;
    float ir = __builtin_amdgcn_rcpf(da * db);
    float ha = fmaf(-2.0f * db, ir, 1.0f);
    float hb = fmaf(-2.0f * da, ir, 1.0f);
    return pack2_bf16_fast(ha, hb);
}

__device__ __forceinline__ float fast_tanh(float x) {
    float e = __builtin_amdgcn_exp2f(x * TANH_C);
    return 1.0f - 2.0f * __builtin_amdgcn_rcpf(1.0f + e);
}

// ---------- kernel P: per-feature-d pack of B = W2g (bf16, 32x32x16 MFMA B order) ----
// W2g[k=d*64+j][n] = sum_o W2[d,j,o] * Wg1[d*64+o, n]
// B-frag for (d, chunk c, n-tile t): lane L holds k = d*64+c*16+(L>>5)*8+j, n = t*32+(L&31).
// flat u32x4 index = ((d*4+c)*2+t)*64 + ((k>>3)&1)*32 + (n&31)
// Also emits cgpart[d][n] into d_out scratch.
__global__ __launch_bounds__(512) void kol_pack(const float* __restrict__ W2,
                                                const float* __restrict__ Wg1,
                                                const float* __restrict__ b2,
                                                uint16_t* __restrict__ Bp,
                                                float* __restrict__ cgpart) {
    __shared__ __align__(16) float w2t[64 * 65];  // [o][j], stride 65
    __shared__ __align__(16) float g1s[64 * 64];  // [o][n]

    const int t = threadIdx.x;
    const int d = blockIdx.x;

    for (int f = t * 4; f < 4096; f += 2048) {
        float4 v = *(const float4*)&W2[(size_t)d * 4096 + f];
        int j = f >> 6, o = f & 63;   // W2[d][j][o..o+3]
        w2t[(o + 0) * 65 + j] = v.x;
        w2t[(o + 1) * 65 + j] = v.y;
        w2t[(o + 2) * 65 + j] = v.z;
        w2t[(o + 3) * 65 + j] = v.w;
        *(float4*)&g1s[f] = *(const float4*)&Wg1[(size_t)d * 4096 + f];
    }
    __syncthreads();

    const int jg = t >> 6;   // j-octet: k = d*64 + jg*8 + jj
    const int n  = t & 63;
    float acc[8];
#pragma unroll
    for (int i = 0; i < 8; ++i) acc[i] = 0.f;

#pragma unroll 4
    for (int o = 0; o < 64; ++o) {
        float g = g1s[o * 64 + n];
        const float* w = &w2t[o * 65 + jg * 8];
#pragma unroll
        for (int jj = 0; jj < 8; ++jj) acc[jj] = fmaf(w[jj], g, acc[jj]);
    }

    u32x4 pk;
    pk.x = pack2_bf16(acc[0], acc[1]);
    pk.y = pack2_bf16(acc[2], acc[3]);
    pk.z = pack2_bf16(acc[4], acc[5]);
    pk.w = pack2_bf16(acc[6], acc[7]);
    // c = jg>>1, hi = jg&1, tile = n>>5
    int off = ((d * 4 + (jg >> 1)) * 2 + (n >> 5)) * 64 + ((jg & 1) << 5) + (n & 31);
    ((u32x4*)Bp)[off] = pk;

    if (t < 64) {
        float a = 0.f;
        const float* b2d = &b2[(size_t)d * 64];
#pragma unroll 4
        for (int o = 0; o < 64; ++o)
            a = fmaf(b2d[o], g1s[o * 64 + t], a);
        cgpart[d * 64 + t] = a;
    }
}

// ---------- kernel R: cg[n] = bg1[n] + sum_d cgpart[d][n] ----------
__global__ __launch_bounds__(256) void kol_reduce_cg(const float* __restrict__ cgpart,
                                                     const float* __restrict__ bg1,
                                                     float* __restrict__ cg) {
    __shared__ float red[4][64];
    const int t = threadIdx.x;
    const int n = t & 63, seg = t >> 6;
    float a = 0.f;
#pragma unroll 4
    for (int d = seg * 16; d < seg * 16 + 16; ++d)
        a += cgpart[d * 64 + n];
    red[seg][n] = a;
    __syncthreads();
    if (t < 64)
        cg[n] = bg1[n] + red[0][n] + red[1][n] + red[2][n] + red[3][n];
}

// ---------- kernel M: main fused GEMM, 32x32x16 MFMA, M=32/wave, K-split x4 ----------
// 512 thr = 8 waves = 2 row-groups(32 rows) x 4 K-quarters(16 d). 64 rows/block,
// 512 blocks. Explicit 2-stage B pipeline (loads for dd+1 issued before dd's MFMAs);
// launch_bounds (512,2) so the allocator keeps the pipeline registers live.
__global__ __launch_bounds__(512, 2) void kol_main(
    const float* __restrict__ x, const float* __restrict__ W1, const float* __restrict__ b1,
    const uint16_t* __restrict__ Bp, const float* __restrict__ cg,
    const float* __restrict__ Wg2, const float* __restrict__ bg2f,
    float* __restrict__ out) {
    __shared__ __align__(16) float smem[12544];   // 50176 B
    float* xs  = smem;            // 64*68 = 4352 floats, pre-scaled x
    float* w1s = smem + 4352;     // 4096
    float* b1s = smem + 8448;     // 4096, pre-scaled by TANH_C
    // combine overlay (after main loop): f32x4 cmb[8][6][64] = 49152 B over smem

    const int tid = threadIdx.x;
    const int wave = tid >> 6, lane = tid & 63;
    const int nn = lane & 31, hi = lane >> 5;
    const int rg = wave & 1, kq = wave >> 1;
    const int rowbase = blockIdx.x * 64;

#pragma unroll
    for (int ff = 0; ff < 2; ++ff) {
        int f = tid * 4 + ff * 2048;
        int r = f >> 6, c = f & 63;
        float4 v = *(const float4*)&x[(size_t)(rowbase + r) * 64 + c];
        v.x *= TANH_C; v.y *= TANH_C; v.z *= TANH_C; v.w *= TANH_C;
        *(float4*)&xs[r * 68 + c] = v;
        *(float4*)&w1s[f] = *(const float4*)&W1[f];
        float4 b = *(const float4*)&b1[f];
        b.x *= TANH_C; b.y *= TANH_C; b.z *= TANH_C; b.w *= TANH_C;
        *(float4*)&b1s[f] = b;
    }
    __syncthreads();

    f32x16 acc0, acc1;
#pragma unroll
    for (int i = 0; i < 16; ++i) { acc0[i] = 0.f; acc1[i] = 0.f; }

    const u32x4* bp = (const u32x4*)Bp + lane;
    const float* xcol = &xs[(rg * 32 + nn) * 68];

    // prime the 2-stage pipeline with d = kq*16
    u32x4 bcur[8];
    {
        const u32x4* bfp0 = bp + (size_t)(kq * 16) * 512;
#pragma unroll
        for (int i = 0; i < 8; ++i) bcur[i] = bfp0[i * 64];
    }

#pragma unroll 2
    for (int dd = 0; dd < 16; ++dd) {
        const int d = kq * 16 + dd;

        // issue next iteration's 8 B-fragment loads (hidden by tanh burst)
        u32x4 bnxt[8];
        const u32x4* bfpn = bp + (size_t)(kq * 16 + ((dd + 1) & 15)) * 512;
#pragma unroll
        for (int i = 0; i < 8; ++i) bnxt[i] = bfpn[i * 64];

        const float xv = xcol[d];
        short8 afr[4];
#pragma unroll
        for (int c = 0; c < 4; ++c) {
            const float* wq = &w1s[d * 64 + c * 16 + hi * 8];
            const float* bq = &b1s[d * 64 + c * 16 + hi * 8];
            float4 w0 = *(const float4*)&wq[0];
            float4 w1v = *(const float4*)&wq[4];
            float4 b0 = *(const float4*)&bq[0];
            float4 b1v = *(const float4*)&bq[4];
            union { short8 s; uint32_t u[4]; } a;
            a.u[0] = tanh2_pack(fmaf(xv, w0.x, b0.x), fmaf(xv, w0.y, b0.y));
            a.u[1] = tanh2_pack(fmaf(xv, w0.z, b0.z), fmaf(xv, w0.w, b0.w));
            a.u[2] = tanh2_pack(fmaf(xv, w1v.x, b1v.x), fmaf(xv, w1v.y, b1v.y));
            a.u[3] = tanh2_pack(fmaf(xv, w1v.z, b1v.z), fmaf(xv, w1v.w, b1v.w));
            afr[c] = a.s;
        }
#pragma unroll
        for (int c = 0; c < 4; ++c) {
            union { u32x4 u; short8 s; } b0c, b1c;
            b0c.u = bcur[c * 2 + 0];
            b1c.u = bcur[c * 2 + 1];
            acc0 = __builtin_amdgcn_mfma_f32_32x32x16_bf16(afr[c], b0c.s, acc0, 0, 0, 0);
            acc1 = __builtin_amdgcn_mfma_f32_32x32x16_bf16(afr[c], b1c.s, acc1, 0, 0, 0);
        }
#pragma unroll
        for (int i = 0; i < 8; ++i) bcur[i] = bnxt[i];
    }

    // ---- combine 4 K-quarter partials through LDS (smem dead) ----
    __syncthreads();
    f32x4* cmb = (f32x4*)smem;   // [s 0..7][widx 0..5][lane]
    if (kq != 0) {
        const int widx = (kq - 1) * 2 + rg;
#pragma unroll
        for (int s = 0; s < 8; ++s) {
            const int base = (s & 3) * 4;
            f32x4 v;
            if (s < 4) v = (f32x4){acc0[base], acc0[base + 1], acc0[base + 2], acc0[base + 3]};
            else       v = (f32x4){acc1[base], acc1[base + 1], acc1[base + 2], acc1[base + 3]};
            cmb[(s * 6 + widx) * 64 + lane] = v;
        }
    }
    __syncthreads();

    if (kq == 0) {
#pragma unroll
        for (int s = 0; s < 8; ++s) {
            const int base = (s & 3) * 4;
            f32x4 v0 = cmb[(s * 6 + 0 + rg) * 64 + lane];
            f32x4 v1 = cmb[(s * 6 + 2 + rg) * 64 + lane];
            f32x4 v2 = cmb[(s * 6 + 4 + rg) * 64 + lane];
            f32x4 v = v0 + v1 + v2;
            if (s < 4) {
#pragma unroll
                for (int i = 0; i < 4; ++i) acc0[base + i] += v[i];
            } else {
#pragma unroll
                for (int i = 0; i < 4; ++i) acc1[base + i] += v[i];
            }
        }
        // epilogue: out[b] = bg2 + sum_n Wg2[n]*tanh(C[b,n]+cg[n])
        // C/D map: col = t*32+nn, row m = (r&3) + 8*(r>>2) + 4*hi
        const float cg0 = cg[nn],      cg1 = cg[32 + nn];
        const float wg0 = Wg2[nn],     wg1 = Wg2[32 + nn];
        const float bg2 = bg2f[0];
#pragma unroll
        for (int g = 0; g < 4; ++g) {
            float4 res;
#pragma unroll
            for (int rr = 0; rr < 4; ++rr) {
                const int r = g * 4 + rr;
                float s = wg0 * fast_tanh(acc0[r] + cg0) + wg1 * fast_tanh(acc1[r] + cg1);
                s += __shfl_xor(s, 1, 64);
                s += __shfl_xor(s, 2, 64);
                s += __shfl_xor(s, 4, 64);
                s += __shfl_xor(s, 8, 64);
                s += __shfl_xor(s, 16, 64);
                ((float*)&res)[rr] = s + bg2;
            }
            if (nn == 0)
                *(float4*)&out[rowbase + rg * 32 + 8 * g + 4 * hi] = res;
        }
    }
}

extern "C" void kernel_launch(void* const* d_in, const int* in_sizes, int n_in,
                              void* d_out, int out_size, void* d_ws, size_t ws_size,
                              hipStream_t stream) {
    const float* x   = (const float*)d_in[0];
    const float* W1  = (const float*)d_in[1];
    const float* b1  = (const float*)d_in[2];
    const float* W2  = (const float*)d_in[3];
    const float* b2  = (const float*)d_in[4];
    const float* Wg1 = (const float*)d_in[5];
    const float* bg1 = (const float*)d_in[6];
    const float* Wg2 = (const float*)d_in[7];
    const float* bg2 = (const float*)d_in[8];
    float* out = (float*)d_out;

    // ws: Bp 512KB + cg 256B (proven budget). cgpart (16KB) in d_out:
    // written by kol_pack, read by kol_reduce_cg, fully overwritten by kol_main.
    uint16_t* Bp  = (uint16_t*)d_ws;
    float* cg     = (float*)((char*)d_ws + 4096 * 64 * 2);
    float* cgpart = out;

    kol_pack<<<64, 512, 0, stream>>>(W2, Wg1, b2, Bp, cgpart);
    kol_reduce_cg<<<1, 256, 0, stream>>>(cgpart, bg1, cg);
    kol_main<<<BATCH / 64, 512, 0, stream>>>(x, W1, b1, Bp, cg, Wg2, bg2, out);
}